// Round 16
// baseline (1833.659 us; speedup 1.0000x reference)
//
#include <hip/hip_runtime.h>
#include <hip/hip_bf16.h>
#include <math.h>
#include <stdint.h>

#define B_ 4
#define M_ 72
#define E_ 24
#define R_ 552
#define L_ 1024
#define H_ 1024
#define A_ 16
#define EMB_ 768
#define BLK_ 64
#define OUT_ 768
#define NC_ 97
#define N_ (B_*R_)        // 2208
#define NPAD_ 2304
#define K2H_ (2*H_)       // 2048
#define KB_ (EMB_/BLK_)   // 12
#define KTOT_ (EMB_*BLK_) // 49152
#define SLICE2_ 524288    // elems per (kb,ob6) W2 slice: 64i x 2wc x 8f x 512

typedef short s16x8 __attribute__((ext_vector_type(8)));
typedef float f32x4 __attribute__((ext_vector_type(4)));
typedef uint32_t u32x4 __attribute__((ext_vector_type(4)));

__device__ __forceinline__ uint32_t pkbf16(float lo, float hi) {
    uint32_t r;
    asm("v_cvt_pk_bf16_f32 %0, %1, %2" : "=v"(r) : "v"(lo), "v"(hi));
    return r;
}
__device__ __forceinline__ unsigned short f2bf(float f) {
    uint32_t u = __builtin_bit_cast(uint32_t, f);
    uint32_t r = (u + 0x7fffu + ((u >> 16) & 1u)) >> 16;
    return (unsigned short)r;
}
__device__ __forceinline__ float bff(unsigned short u) {
    return __builtin_bit_cast(float, (uint32_t)u << 16);
}
__device__ __forceinline__ void gload_lds16(const void* g, void* l) {
    __builtin_amdgcn_global_load_lds(
        (const __attribute__((address_space(1))) unsigned int*)g,
        (__attribute__((address_space(3))) unsigned int*)l, 16, 0, 0);
}

// ---------------- pooling: ent_emb (logsumexp, bf16) + amean (bf16) ----------------
__global__ void k_pool(const float* __restrict__ ent_lhs,
                       const float* __restrict__ attn,
                       const int*   __restrict__ labels,
                       unsigned short* __restrict__ ent_bf,   // B,E,H
                       unsigned short* __restrict__ amean_bf) // B,E,A,L
{
    int b = blockIdx.x / E_;
    int e = blockIdx.x % E_;
    __shared__ int mlist[M_];
    __shared__ int mcount;
    if (threadIdx.x == 0) {
        int c = 0;
        for (int m = 0; m < M_; ++m)
            if (labels[b*M_ + m] == e) mlist[c++] = m;
        mcount = c;
    }
    __syncthreads();
    int cnt = mcount;

    for (int h = threadIdx.x; h < H_; h += blockDim.x) {
        float out = 0.f;
        if (cnt > 0) {
            float mx = -INFINITY;
            for (int q = 0; q < cnt; ++q)
                mx = fmaxf(mx, ent_lhs[(size_t)(b*M_ + mlist[q])*H_ + h]);
            float s = 0.f;
            for (int q = 0; q < cnt; ++q)
                s += expf(ent_lhs[(size_t)(b*M_ + mlist[q])*H_ + h] - mx);
            out = logf(s) + mx;
        }
        ent_bf[(size_t)(b*E_ + e)*H_ + h] = f2bf(out);
    }

    float inv = (cnt > 0) ? (1.f / (float)cnt) : 0.f;
    for (int c4 = threadIdx.x; c4 < A_*(L_/4); c4 += blockDim.x) {
        int a = c4 / (L_/4), l4 = c4 % (L_/4);
        float sx = 0.f, sy = 0.f, sz = 0.f, sw = 0.f;
        for (int q = 0; q < cnt; ++q) {
            float4 v = *(const float4*)(attn + ((size_t)(b*A_ + a)*M_ + mlist[q])*L_ + l4*4);
            sx += v.x; sy += v.y; sz += v.z; sw += v.w;
        }
        ushort4 o;
        o.x = f2bf(sx*inv); o.y = f2bf(sy*inv); o.z = f2bf(sz*inv); o.w = f2bf(sw*inv);
        *(ushort4*)(amean_bf + ((size_t)(b*E_ + e)*A_ + a)*L_ + l4*4) = o;
    }
}

// ---------------- ht_attn (bf16 in/out) ----------------
__global__ void k_htattn(const unsigned short* __restrict__ amean_bf, // B,E,A,L
                         const int* __restrict__ hts,
                         unsigned short* __restrict__ htw_bf)         // B,R,L
{
    int br = blockIdx.x;
    int b  = br / R_;
    int hh = hts[br*2 + 0], tt = hts[br*2 + 1];
    const unsigned short* pa = amean_bf + (size_t)(b*E_ + hh)*A_*L_;
    const unsigned short* pb = amean_bf + (size_t)(b*E_ + tt)*A_*L_;

    int l0 = threadIdx.x * 4;
    float v[4] = {0.f, 0.f, 0.f, 0.f};
    for (int a = 0; a < A_; ++a) {
        ushort4 ua = *(const ushort4*)(pa + (size_t)a*L_ + l0);
        ushort4 ub = *(const ushort4*)(pb + (size_t)a*L_ + l0);
        v[0] += bff(ua.x)*bff(ub.x); v[1] += bff(ua.y)*bff(ub.y);
        v[2] += bff(ua.z)*bff(ub.z); v[3] += bff(ua.w)*bff(ub.w);
    }
    float part = (v[0]+v[1]+v[2]+v[3]) * 0.0625f;
    __shared__ float red[256];
    red[threadIdx.x] = part;
    __syncthreads();
    for (int st = 128; st > 0; st >>= 1) {
        if (threadIdx.x < st) red[threadIdx.x] += red[threadIdx.x + st];
        __syncthreads();
    }
    float norm = 0.0625f / (red[0] + 1e-5f);
    unsigned short* po = htw_bf + (size_t)br*L_ + l0;
    po[0] = f2bf(v[0]*norm); po[1] = f2bf(v[1]*norm);
    po[2] = f2bf(v[2]*norm); po[3] = f2bf(v[3]*norm);
}

// ---------------- generic transpose+cvt: in f32 [z][K][O] -> out bf16 [z][O][K] ----------------
__global__ void k_transcvt(const float* __restrict__ W, unsigned short* __restrict__ Wt,
                           int K, int O)
{
    const float* src = W + (size_t)blockIdx.z*K*O;
    unsigned short* dst = Wt + (size_t)blockIdx.z*K*O;
    __shared__ unsigned short t[64][72];
    int k0 = blockIdx.x * 64, o0 = blockIdx.y * 64;
    #pragma unroll
    for (int p = 0; p < 16; ++p) {
        int idx = p*256 + threadIdx.x;
        int r = idx >> 6, c = idx & 63;
        t[c][r] = f2bf(src[(size_t)(k0 + r)*O + o0 + c]);
    }
    __syncthreads();
    #pragma unroll
    for (int p = 0; p < 16; ++p) {
        int idx = p*256 + threadIdx.x;
        int r = idx >> 6, c = idx & 63;
        dst[(size_t)(o0 + r)*K + k0 + c] = t[r][c];
    }
}

// ---------------- W_bil f32 [49152][768] -> W2 bf16 fragment layout ----------------
// W2[s=kb*6+ob][i][wc][f=jh*4+of][lane][e], slice = 1 MB
// elem (lane,e) of frag f = W[(kb*64+i)*64 + j][ob*128 + wc*64 + of*16 + (lane&15)]
// with j = (jh*4 + (lane>>4))*8 + e
__global__ void k_cvtW2(const float* __restrict__ W, unsigned short* __restrict__ W2)
{
    __shared__ unsigned short t[64][72];
    int k0 = blockIdx.x * 64, o0 = blockIdx.y * 64;
    #pragma unroll
    for (int p = 0; p < 16; ++p) {
        int idx = p*256 + threadIdx.x;
        int r = idx >> 6, c = idx & 63;          // r: k-local (j), c: o-local
        t[c][r] = f2bf(W[(size_t)(k0 + r)*OUT_ + o0 + c]);
    }
    __syncthreads();
    int kb = k0 >> 12;
    int i  = (k0 >> 6) & 63;
    int ob = o0 >> 7;
    int wc = (o0 >> 6) & 1;
    unsigned short* base = W2 + (size_t)(kb*6 + ob)*SLICE2_ + i*8192 + wc*4096;
    #pragma unroll
    for (int p = 0; p < 16; ++p) {
        int lin = p*256 + threadIdx.x;           // 0..4095
        int e = lin & 7;
        int lane = (lin >> 3) & 63;
        int f = lin >> 9;                        // 0..7 = jh*4 + ofl
        int jh = f >> 2, ofl = f & 3;
        int j = (jh*4 + (lane >> 4))*8 + e;
        int o_local = ofl*16 + (lane & 15);
        base[f*512 + lane*8 + e] = t[o_local][j];
    }
}

// ---------------- merged init: pacc biases + embeds bias + WcatT ----------------
__global__ void k_init(const float* __restrict__ b_head, const float* __restrict__ b_tail,
                       const float* __restrict__ b_bil,
                       const float* __restrict__ Wc, const float* __restrict__ Wbn,
                       float* __restrict__ pacc, float* __restrict__ embeds,
                       unsigned short* __restrict__ WcatT)
{
    int idx = blockIdx.x * 256 + threadIdx.x;
    if (idx < 2*NPAD_*OUT_) {
        const float* bb = (idx < NPAD_*OUT_) ? b_head : b_tail;
        pacc[idx] = bb[idx % OUT_];
    } else if (idx < 2*NPAD_*OUT_ + N_*OUT_) {
        int j = idx - 2*NPAD_*OUT_;
        embeds[j] = b_bil[j % OUT_];
    } else {
        int j = idx - 2*NPAD_*OUT_ - N_*OUT_;
        if (j < 256*768) {
            int o = j / 768, k = j % 768;
            float v = 0.f;
            if (o < NC_) v = Wc[(size_t)k*NC_ + o];
            else if (o == NC_) v = Wbn[k];
            WcatT[j] = f2bf(v);
        }
    }
}

// ---------------- rel = ht_attn @ seq : MFMA, BN=128, reg-prefetch ----------------
__global__ __launch_bounds__(256, 2)
void k_rel_mfma(const unsigned short* __restrict__ htw,   // B,R,L
                const unsigned short* __restrict__ seqT,  // B,H,L
                unsigned short* __restrict__ rel_bf)      // N,H
{
    int bid = blockIdx.x;
    int ot = bid & 7;
    int rest = bid >> 3;
    int mt = rest % 5;
    int b  = rest / 5;
    int m0 = mt*128, o0 = ot*128;
    int tid = threadIdx.x, lane = tid & 63, wid = tid >> 6;
    int wr = wid >> 1, wc = wid & 1;
    __shared__ __align__(16) unsigned short a_s[128*64];
    __shared__ __align__(16) unsigned short b_s[128*64];
    const unsigned short* Ab = htw + (size_t)b*R_*L_;
    const unsigned short* Bb = seqT + (size_t)b*H_*L_;

    u32x4 aR[4], bR[4];
    auto loadA = [&](int st) {
        #pragma unroll
        for (int q = 0; q < 4; ++q) {
            int slot = q*256 + tid;
            int r = slot >> 3, s = slot & 7;
            int ar = m0 + r; if (ar > R_-1) ar = R_-1;
            aR[q] = *(const u32x4*)(Ab + (size_t)ar*L_ + st*64 + s*8);
        }
    };
    auto loadB = [&](int st) {
        #pragma unroll
        for (int q = 0; q < 4; ++q) {
            int slot = q*256 + tid;
            int o = slot >> 3, s = slot & 7;
            bR[q] = *(const u32x4*)(Bb + (size_t)(o0+o)*L_ + st*64 + s*8);
        }
    };

    f32x4 acc[4][4];
    const f32x4 zz = {0.f,0.f,0.f,0.f};
    #pragma unroll
    for (int mf = 0; mf < 4; ++mf)
        #pragma unroll
        for (int of = 0; of < 4; ++of) acc[mf][of] = zz;

    loadA(0); loadB(0);
    for (int st = 0; st < 16; ++st) {
        __syncthreads();
        #pragma unroll
        for (int q = 0; q < 4; ++q) {
            int slot = q*256 + tid; int r = slot >> 3, s = slot & 7;
            *(u32x4*)((char*)a_s + r*128 + ((s ^ (r & 7)) << 4)) = aR[q];
        }
        #pragma unroll
        for (int q = 0; q < 4; ++q) {
            int slot = q*256 + tid; int o = slot >> 3, s = slot & 7;
            *(u32x4*)((char*)b_s + o*128 + ((s ^ (o & 7)) << 4)) = bR[q];
        }
        __syncthreads();
        if (st < 15) { loadA(st+1); loadB(st+1); }
        #pragma unroll
        for (int kh = 0; kh < 2; ++kh) {
            s16x8 af[4];
            #pragma unroll
            for (int mf = 0; mf < 4; ++mf) {
                int r = wr*64 + mf*16 + (lane & 15);
                int s = kh*4 + (lane >> 4);
                af[mf] = *(const s16x8*)((const char*)a_s + r*128 + ((s ^ (r & 7)) << 4));
            }
            #pragma unroll
            for (int of = 0; of < 4; ++of) {
                int ol = wc*64 + of*16 + (lane & 15);
                int s = kh*4 + (lane >> 4);
                s16x8 bfr = *(const s16x8*)((const char*)b_s + ol*128 + ((s ^ (ol & 7)) << 4));
                #pragma unroll
                for (int mf = 0; mf < 4; ++mf)
                    acc[mf][of] = __builtin_amdgcn_mfma_f32_16x16x32_bf16(
                        af[mf], bfr, acc[mf][of], 0, 0, 0);
            }
        }
    }
    #pragma unroll
    for (int mf = 0; mf < 4; ++mf)
        #pragma unroll
        for (int of = 0; of < 4; ++of) {
            int col = o0 + wc*64 + of*16 + (lane & 15);
            #pragma unroll
            for (int rr = 0; rr < 4; ++rr) {
                int row = m0 + wr*64 + mf*16 + (lane >> 4)*4 + rr;
                if (row < R_)
                    rel_bf[((size_t)b*R_ + row)*H_ + col] = f2bf(acc[mf][of][rr]);
            }
        }
}

// ---------------- head/tail projection MFMA, reg-prefetch ----------------
__global__ __launch_bounds__(256, 2)
void k_proj_mfma(const unsigned short* __restrict__ ent_bf,
                 const unsigned short* __restrict__ rel_bf,
                 const int* __restrict__ hts,
                 const unsigned short* __restrict__ Wph,   // 768 x 2048
                 const unsigned short* __restrict__ Wpt,
                 float* __restrict__ pacc)
{
    int bid = blockIdx.x;
    int kq = bid & 3;
    int rest = bid >> 2;
    int ob = rest % 3;  rest /= 3;
    int mb = rest % 18;
    int which = rest / 18;
    int m0 = mb * 128, o0 = ob * 256;
    const unsigned short* Wp = which ? Wpt : Wph;
    float* out = pacc + (size_t)which*NPAD_*OUT_;
    int tid = threadIdx.x, lane = tid & 63, wid = tid >> 6;
    int wr = wid >> 1, wc = wid & 1;
    __shared__ __align__(16) unsigned short a_s[128*64];
    __shared__ __align__(16) unsigned short b_s[256*64];

    bool enthalf = (kq < 2);
    const unsigned short* abase[4];
    #pragma unroll
    for (int q = 0; q < 4; ++q) {
        int slot = q*256 + tid;
        int r = slot >> 3;
        int n = m0 + r;
        int nn = (n < N_) ? n : (N_ - 1);
        if (enthalf) {
            int bb = nn / R_;
            abase[q] = ent_bf + (size_t)(bb*E_ + hts[nn*2 + which])*H_ + kq*512;
        } else {
            abase[q] = rel_bf + (size_t)nn*H_ + (kq - 2)*512;
        }
    }
    u32x4 aR[4], bR[8];
    auto loadA = [&](int st) {
        #pragma unroll
        for (int q = 0; q < 4; ++q) {
            int s = (q*256 + tid) & 7;
            aR[q] = *(const u32x4*)(abase[q] + st*64 + s*8);
        }
    };
    auto loadB = [&](int st) {
        #pragma unroll
        for (int q = 0; q < 8; ++q) {
            int slot = q*256 + tid;
            int o = slot >> 3, s = slot & 7;
            bR[q] = *(const u32x4*)(Wp + (size_t)(o0+o)*K2H_ + kq*512 + st*64 + s*8);
        }
    };

    f32x4 acc[4][8];
    const f32x4 zz = {0.f,0.f,0.f,0.f};
    #pragma unroll
    for (int mf = 0; mf < 4; ++mf)
        #pragma unroll
        for (int of = 0; of < 8; ++of) acc[mf][of] = zz;

    loadA(0); loadB(0);
    for (int st = 0; st < 8; ++st) {
        __syncthreads();
        #pragma unroll
        for (int q = 0; q < 4; ++q) {
            int slot = q*256 + tid; int r = slot >> 3, s = slot & 7;
            *(u32x4*)((char*)a_s + r*128 + ((s ^ (r & 7)) << 4)) = aR[q];
        }
        #pragma unroll
        for (int q = 0; q < 8; ++q) {
            int slot = q*256 + tid; int o = slot >> 3, s = slot & 7;
            *(u32x4*)((char*)b_s + o*128 + ((s ^ (o & 7)) << 4)) = bR[q];
        }
        __syncthreads();
        if (st < 7) { loadA(st+1); loadB(st+1); }
        #pragma unroll
        for (int kh = 0; kh < 2; ++kh) {
            s16x8 af[4];
            #pragma unroll
            for (int mf = 0; mf < 4; ++mf) {
                int r = wr*64 + mf*16 + (lane & 15);
                int s = kh*4 + (lane >> 4);
                af[mf] = *(const s16x8*)((const char*)a_s + r*128 + ((s ^ (r & 7)) << 4));
            }
            #pragma unroll
            for (int of = 0; of < 8; ++of) {
                int ol = wc*128 + of*16 + (lane & 15);
                int s = kh*4 + (lane >> 4);
                s16x8 bfr = *(const s16x8*)((const char*)b_s + ol*128 + ((s ^ (ol & 7)) << 4));
                #pragma unroll
                for (int mf = 0; mf < 4; ++mf)
                    acc[mf][of] = __builtin_amdgcn_mfma_f32_16x16x32_bf16(
                        af[mf], bfr, acc[mf][of], 0, 0, 0);
            }
        }
    }
    #pragma unroll
    for (int mf = 0; mf < 4; ++mf)
        #pragma unroll
        for (int of = 0; of < 8; ++of) {
            int col = o0 + wc*128 + of*16 + (lane & 15);
            #pragma unroll
            for (int rr = 0; rr < 4; ++rr) {
                int row = m0 + wr*64 + mf*16 + (lane >> 4)*4 + rr;
                atomicAdd(&out[(size_t)row*OUT_ + col], acc[mf][of][rr]);
            }
        }
}

// ---------------- tanh + cvt ----------------
__global__ void k_tanhcvt(const float* __restrict__ pacc,
                          unsigned short* __restrict__ hsp,
                          unsigned short* __restrict__ tsp)
{
    int idx = blockIdx.x * 256 + threadIdx.x;
    if (idx < NPAD_*OUT_) {
        hsp[idx] = f2bf(tanhf(pacc[idx]));
        tsp[idx] = f2bf(tanhf(pacc[NPAD_*OUT_ + idx]));
    }
}

// ---------------- bilinear MFMA GEMM (round-12 structure, launch_bounds(256,4)) ----------------
// grid 1296 = 8 XCD x 9 g x 18 mb; slice s = g*8+x in [0,72): kb = s/6, ob = s%6.
// Block 128M x 128o, 4 waves (2wr x 2wc), wave 64x64 (Fm=4, Fo=4).
// W2 frags loaded straight to registers (L2-resident), 2-deep named dbuf, no K-loop barriers.
// bounds (256,4): VGPR cap 128 >= 112 used (no spill; r10's disaster needed ~150+);
// 4 blocks/CU resident -> cross-wave VALU/MFMA overlap (m114) hides the ~19% stall.
__global__ __launch_bounds__(256, 4)
void k_bilinear_mfma(const unsigned short* __restrict__ hsp,
                     const unsigned short* __restrict__ tsp,
                     const unsigned short* __restrict__ W2,
                     float* __restrict__ embeds)
{
    int bid = blockIdx.x;
    int x = bid & 7, rest = bid >> 3;     // rest 0..161
    int g = rest / 18, mb = rest % 18;    // g 0..8
    int s = g*8 + x;                      // 0..71
    int kb = s / 6, ob = s % 6;
    int m0 = mb * 128;
    int tid = threadIdx.x, lane = tid & 63, wid = tid >> 6;
    int wr = wid >> 1, wc = wid & 1;

    __shared__ __align__(16) unsigned short hs_s[128*64];  // 16 KB
    __shared__ __align__(16) unsigned short ts_s[128*64];  // 16 KB

    // ---- prologue: stage hs/ts tiles (XOR-swizzled src, linear dst) ----
    #pragma unroll
    for (int q = 0; q < 4; ++q) {
        int slot = q*256 + tid;
        int r = slot >> 3, s7 = slot & 7;
        int gg = s7 ^ (r & 7);
        size_t srcoff = (size_t)(m0 + r)*EMB_ + kb*64 + (gg << 3);
        gload_lds16(hsp + srcoff, (char*)hs_s + (q*4096 + wid*1024));
        gload_lds16(tsp + srcoff, (char*)ts_s + (q*4096 + wid*1024));
    }
    __syncthreads();

    // ---- ts fragments -> unpacked f32 regs (Fm=4) ----
    float tsf[4][2][8];
    #pragma unroll
    for (int mf = 0; mf < 4; ++mf) {
        int r = wr*64 + mf*16 + (lane & 15);
        #pragma unroll
        for (int jh = 0; jh < 2; ++jh) {
            int s8 = jh*4 + (lane >> 4);
            u32x4 tv = *(const u32x4*)((const char*)ts_s + r*128 + ((s8 ^ (r & 7)) << 4));
            #pragma unroll
            for (int p = 0; p < 4; ++p) {
                tsf[mf][jh][2*p]   = __builtin_bit_cast(float, tv[p] << 16);
                tsf[mf][jh][2*p+1] = __builtin_bit_cast(float, tv[p] & 0xffff0000u);
            }
        }
    }

    const unsigned short* Wsl = W2 + (size_t)s * SLICE2_ + wc*4096 + lane*8;

    f32x4 acc[4][4];
    const f32x4 zz = {0.f, 0.f, 0.f, 0.f};
    #pragma unroll
    for (int mf = 0; mf < 4; ++mf)
        #pragma unroll
        for (int of = 0; of < 4; ++of) acc[mf][of] = zz;

    u32x4 bA[8], bB[8];
    auto loadB = [&](int i, u32x4 (&buf)[8]) {
        const unsigned short* src = Wsl + (size_t)i*8192;
        #pragma unroll
        for (int f = 0; f < 8; ++f)
            buf[f] = *(const u32x4*)(src + f*512);
    };
    auto compute = [&](int i, u32x4 (&buf)[8]) {
        float hsf[4];
        #pragma unroll
        for (int mf = 0; mf < 4; ++mf) {
            int r = wr*64 + mf*16 + (lane & 15);
            int hb = r*128 + ((((i >> 3)) ^ (r & 7)) << 4) + (i & 7)*2;
            hsf[mf] = bff(*(const unsigned short*)((const char*)hs_s + hb));
        }
        #pragma unroll
        for (int jh = 0; jh < 2; ++jh) {
            s16x8 afr[4];
            #pragma unroll
            for (int mf = 0; mf < 4; ++mf) {
                u32x4 a;
                #pragma unroll
                for (int p = 0; p < 4; ++p)
                    a[p] = pkbf16(hsf[mf]*tsf[mf][jh][2*p], hsf[mf]*tsf[mf][jh][2*p+1]);
                afr[mf] = __builtin_bit_cast(s16x8, a);
            }
            __builtin_amdgcn_s_setprio(1);
            #pragma unroll
            for (int of = 0; of < 4; ++of) {
                s16x8 bfr = __builtin_bit_cast(s16x8, buf[jh*4 + of]);
                #pragma unroll
                for (int mf = 0; mf < 4; ++mf)
                    acc[mf][of] = __builtin_amdgcn_mfma_f32_16x16x32_bf16(
                        afr[mf], bfr, acc[mf][of], 0, 0, 0);
            }
            __builtin_amdgcn_s_setprio(0);
        }
    };

    loadB(0, bA);
    for (int i2 = 0; i2 < 32; ++i2) {
        loadB(2*i2 + 1, bB);               // prefetch odd
        compute(2*i2, bA);
        if (i2 < 31) loadB(2*i2 + 2, bA);  // prefetch next even
        compute(2*i2 + 1, bB);
    }

    // ---- atomic accumulate ----
    #pragma unroll
    for (int mf = 0; mf < 4; ++mf) {
        #pragma unroll
        for (int of = 0; of < 4; ++of) {
            int col = ob*128 + wc*64 + of*16 + (lane & 15);
            #pragma unroll
            for (int rr = 0; rr < 4; ++rr) {
                int row = wr*64 + mf*16 + (lane >> 4)*4 + rr;
                int n = m0 + row;
                if (n < N_)
                    atomicAdd(&embeds[(size_t)n*OUT_ + col], acc[mf][of][rr]);
            }
        }
    }
}

// ---------------- logits MFMA: reads f32 embeds directly (cvt in reg-staging) ----------------
__global__ __launch_bounds__(256, 2)
void k_logits_mfma(const float* __restrict__ embeds,        // N x 768 f32
                   const unsigned short* __restrict__ WcatT,// 256 x 768 bf16
                   const float* __restrict__ bc, const float* __restrict__ bbn,
                   float* __restrict__ cls, float* __restrict__ bin)
{
    int m0 = blockIdx.x * 128;
    int tid = threadIdx.x, lane = tid & 63, wid = tid >> 6;
    int wr = wid >> 1, wc = wid & 1;
    __shared__ __align__(16) unsigned short a_s[128*64];
    __shared__ __align__(16) unsigned short b_s[256*64];

    u32x4 aR[4], bR[8];
    auto loadA = [&](int st) {
        #pragma unroll
        for (int q = 0; q < 4; ++q) {
            int slot = q*256 + tid;
            int r = slot >> 3, s = slot & 7;
            int ar = m0 + r; if (ar > N_-1) ar = N_-1;
            const float* src = embeds + (size_t)ar*OUT_ + st*64 + s*8;
            float4 v0 = *(const float4*)(src);
            float4 v1 = *(const float4*)(src + 4);
            u32x4 a;
            a[0] = pkbf16(v0.x, v0.y); a[1] = pkbf16(v0.z, v0.w);
            a[2] = pkbf16(v1.x, v1.y); a[3] = pkbf16(v1.z, v1.w);
            aR[q] = a;
        }
    };
    auto loadB = [&](int st) {
        #pragma unroll
        for (int q = 0; q < 8; ++q) {
            int slot = q*256 + tid;
            int o = slot >> 3, s = slot & 7;
            bR[q] = *(const u32x4*)(WcatT + (size_t)o*OUT_ + st*64 + s*8);
        }
    };

    f32x4 acc[4][8];
    const f32x4 zz = {0.f,0.f,0.f,0.f};
    #pragma unroll
    for (int mf = 0; mf < 4; ++mf)
        #pragma unroll
        for (int of = 0; of < 8; ++of) acc[mf][of] = zz;

    loadA(0); loadB(0);
    for (int st = 0; st < 12; ++st) {
        __syncthreads();
        #pragma unroll
        for (int q = 0; q < 4; ++q) {
            int slot = q*256 + tid; int r = slot >> 3, s = slot & 7;
            *(u32x4*)((char*)a_s + r*128 + ((s ^ (r & 7)) << 4)) = aR[q];
        }
        #pragma unroll
        for (int q = 0; q < 8; ++q) {
            int slot = q*256 + tid; int o = slot >> 3, s = slot & 7;
            *(u32x4*)((char*)b_s + o*128 + ((s ^ (o & 7)) << 4)) = bR[q];
        }
        __syncthreads();
        if (st < 11) { loadA(st+1); loadB(st+1); }
        #pragma unroll
        for (int kh = 0; kh < 2; ++kh) {
            s16x8 af[4];
            #pragma unroll
            for (int mf = 0; mf < 4; ++mf) {
                int r = wr*64 + mf*16 + (lane & 15);
                int s = kh*4 + (lane >> 4);
                af[mf] = *(const s16x8*)((const char*)a_s + r*128 + ((s ^ (r & 7)) << 4));
            }
            #pragma unroll
            for (int of = 0; of < 8; ++of) {
                int ol = wc*128 + of*16 + (lane & 15);
                int s = kh*4 + (lane >> 4);
                s16x8 bfr = *(const s16x8*)((const char*)b_s + ol*128 + ((s ^ (ol & 7)) << 4));
                #pragma unroll
                for (int mf = 0; mf < 4; ++mf)
                    acc[mf][of] = __builtin_amdgcn_mfma_f32_16x16x32_bf16(
                        af[mf], bfr, acc[mf][of], 0, 0, 0);
            }
        }
    }
    #pragma unroll
    for (int mf = 0; mf < 4; ++mf)
        #pragma unroll
        for (int of = 0; of < 8; ++of) {
            int col = wc*128 + of*16 + (lane & 15);
            if (col <= NC_) {
                #pragma unroll
                for (int rr = 0; rr < 4; ++rr) {
                    int row = m0 + wr*64 + mf*16 + (lane >> 4)*4 + rr;
                    if (row < N_) {
                        float v = acc[mf][of][rr];
                        if (col < NC_) cls[(size_t)row*NC_ + col] = v + bc[col];
                        else           bin[row] = v + bbn[0];
                    }
                }
            }
        }
}

extern "C" void kernel_launch(void* const* d_in, const int* in_sizes, int n_in,
                              void* d_out, int out_size, void* d_ws, size_t ws_size,
                              hipStream_t stream) {
    const float* seq_lhs = (const float*)d_in[0];
    const float* ent_lhs = (const float*)d_in[1];
    const float* attn    = (const float*)d_in[2];
    const int*   labels  = (const int*)d_in[3];
    const int*   hts     = (const int*)d_in[4];
    const float* W_head  = (const float*)d_in[5];
    const float* b_head  = (const float*)d_in[6];
    const float* W_tail  = (const float*)d_in[7];
    const float* b_tail  = (const float*)d_in[8];
    const float* W_bil   = (const float*)d_in[9];
    const float* b_bil   = (const float*)d_in[10];
    const float* W_cls   = (const float*)d_in[11];
    const float* b_cls   = (const float*)d_in[12];
    const float* W_bin   = (const float*)d_in[13];
    const float* b_bin   = (const float*)d_in[14];

    float* out_embeds = (float*)d_out;
    float* out_cls    = out_embeds + (size_t)N_*OUT_;
    float* out_bin    = out_cls + (size_t)N_*NC_;

    float* ws = (float*)d_ws;
    size_t off = 0;
    unsigned short* ent_bf   = (unsigned short*)(ws + off); off += (size_t)B_*E_*H_/2;
    float* pacc = ws + off;   // overlays amean_bf + htw_bf + seqT (dead by then)
    unsigned short* amean_bf = (unsigned short*)(ws + off); off += (size_t)B_*E_*A_*L_/2;
    unsigned short* htw_bf   = (unsigned short*)(ws + off); off += (size_t)B_*R_*L_/2;
    unsigned short* seqT     = (unsigned short*)(ws + off); off += (size_t)B_*H_*L_/2;
    unsigned short* rel_bf   = (unsigned short*)(ws + off); off += (size_t)N_*H_/2;
    unsigned short* hsp      = (unsigned short*)(ws + off); off += (size_t)NPAD_*EMB_/2;
    unsigned short* tsp      = (unsigned short*)(ws + off); off += (size_t)NPAD_*EMB_/2;
    unsigned short* W2       = (unsigned short*)(ws + off); off += (size_t)OUT_*KTOT_/2;
    unsigned short* Wph      = (unsigned short*)(ws + off); off += (size_t)OUT_*K2H_/2;
    unsigned short* Wpt      = (unsigned short*)(ws + off); off += (size_t)OUT_*K2H_/2;
    unsigned short* WcatT    = (unsigned short*)(ws + off); off += (size_t)256*768/2;

    // weight / input conversions
    k_cvtW2<<<dim3(KTOT_/64, OUT_/64), 256, 0, stream>>>(W_bil, W2);
    k_transcvt<<<dim3(K2H_/64, OUT_/64, 1), 256, 0, stream>>>(W_head, Wph, K2H_, OUT_);
    k_transcvt<<<dim3(K2H_/64, OUT_/64, 1), 256, 0, stream>>>(W_tail, Wpt, K2H_, OUT_);
    k_transcvt<<<dim3(L_/64, H_/64, B_), 256, 0, stream>>>(seq_lhs, seqT, L_, H_);

    k_pool<<<B_*E_, 256, 0, stream>>>(ent_lhs, attn, labels, ent_bf, amean_bf);
    k_htattn<<<B_*R_, 256, 0, stream>>>(amean_bf, hts, htw_bf);
    k_rel_mfma<<<160, 256, 0, stream>>>(htw_bf, seqT, rel_bf);

    // pacc overlays amean/htw/seqT -- init only after k_rel consumed them
    int init_elems = 2*NPAD_*OUT_ + N_*OUT_ + 256*768;
    k_init<<<(init_elems + 255)/256, 256, 0, stream>>>(b_head, b_tail, b_bil,
                                                       W_cls, W_bin,
                                                       pacc, out_embeds, WcatT);
    k_proj_mfma<<<2*18*3*4, 256, 0, stream>>>(ent_bf, rel_bf, hts, Wph, Wpt, pacc);
    k_tanhcvt<<<(NPAD_*OUT_ + 255)/256, 256, 0, stream>>>(pacc, hsp, tsp);

    k_bilinear_mfma<<<1296, 256, 0, stream>>>(hsp, tsp, W2, out_embeds);

    k_logits_mfma<<<18, 256, 0, stream>>>(out_embeds, WcatT, b_cls, b_bin,
                                          out_cls, out_bin);
}

// Round 17
// 459.529 us; speedup vs baseline: 3.9903x; 3.9903x over previous
//
#include <hip/hip_runtime.h>
#include <hip/hip_bf16.h>
#include <math.h>
#include <stdint.h>

#define B_ 4
#define M_ 72
#define E_ 24
#define R_ 552
#define L_ 1024
#define H_ 1024
#define A_ 16
#define EMB_ 768
#define BLK_ 64
#define OUT_ 768
#define NC_ 97
#define N_ (B_*R_)        // 2208
#define NPAD_ 2304
#define K2H_ (2*H_)       // 2048
#define KB_ (EMB_/BLK_)   // 12
#define KTOT_ (EMB_*BLK_) // 49152
#define SLICE2_ 524288    // elems per (kb,ob6) W2 slice: 64i x 2wc x 8f x 512

typedef short s16x8 __attribute__((ext_vector_type(8)));
typedef float f32x4 __attribute__((ext_vector_type(4)));
typedef uint32_t u32x4 __attribute__((ext_vector_type(4)));

__device__ __forceinline__ uint32_t pkbf16(float lo, float hi) {
    uint32_t r;
    asm("v_cvt_pk_bf16_f32 %0, %1, %2" : "=v"(r) : "v"(lo), "v"(hi));
    return r;
}
__device__ __forceinline__ unsigned short f2bf(float f) {
    uint32_t u = __builtin_bit_cast(uint32_t, f);
    uint32_t r = (u + 0x7fffu + ((u >> 16) & 1u)) >> 16;
    return (unsigned short)r;
}
__device__ __forceinline__ float bff(unsigned short u) {
    return __builtin_bit_cast(float, (uint32_t)u << 16);
}
__device__ __forceinline__ void gload_lds16(const void* g, void* l) {
    __builtin_amdgcn_global_load_lds(
        (const __attribute__((address_space(1))) unsigned int*)g,
        (__attribute__((address_space(3))) unsigned int*)l, 16, 0, 0);
}

// ---------------- pooling: ent_emb (logsumexp, bf16) + amean (bf16) ----------------
__global__ void k_pool(const float* __restrict__ ent_lhs,
                       const float* __restrict__ attn,
                       const int*   __restrict__ labels,
                       unsigned short* __restrict__ ent_bf,   // B,E,H
                       unsigned short* __restrict__ amean_bf) // B,E,A,L
{
    int b = blockIdx.x / E_;
    int e = blockIdx.x % E_;
    __shared__ int mlist[M_];
    __shared__ int mcount;
    if (threadIdx.x == 0) {
        int c = 0;
        for (int m = 0; m < M_; ++m)
            if (labels[b*M_ + m] == e) mlist[c++] = m;
        mcount = c;
    }
    __syncthreads();
    int cnt = mcount;

    for (int h = threadIdx.x; h < H_; h += blockDim.x) {
        float out = 0.f;
        if (cnt > 0) {
            float mx = -INFINITY;
            for (int q = 0; q < cnt; ++q)
                mx = fmaxf(mx, ent_lhs[(size_t)(b*M_ + mlist[q])*H_ + h]);
            float s = 0.f;
            for (int q = 0; q < cnt; ++q)
                s += expf(ent_lhs[(size_t)(b*M_ + mlist[q])*H_ + h] - mx);
            out = logf(s) + mx;
        }
        ent_bf[(size_t)(b*E_ + e)*H_ + h] = f2bf(out);
    }

    float inv = (cnt > 0) ? (1.f / (float)cnt) : 0.f;
    for (int c4 = threadIdx.x; c4 < A_*(L_/4); c4 += blockDim.x) {
        int a = c4 / (L_/4), l4 = c4 % (L_/4);
        float sx = 0.f, sy = 0.f, sz = 0.f, sw = 0.f;
        for (int q = 0; q < cnt; ++q) {
            float4 v = *(const float4*)(attn + ((size_t)(b*A_ + a)*M_ + mlist[q])*L_ + l4*4);
            sx += v.x; sy += v.y; sz += v.z; sw += v.w;
        }
        ushort4 o;
        o.x = f2bf(sx*inv); o.y = f2bf(sy*inv); o.z = f2bf(sz*inv); o.w = f2bf(sw*inv);
        *(ushort4*)(amean_bf + ((size_t)(b*E_ + e)*A_ + a)*L_ + l4*4) = o;
    }
}

// ---------------- ht_attn (bf16 in/out) ----------------
__global__ void k_htattn(const unsigned short* __restrict__ amean_bf, // B,E,A,L
                         const int* __restrict__ hts,
                         unsigned short* __restrict__ htw_bf)         // B,R,L
{
    int br = blockIdx.x;
    int b  = br / R_;
    int hh = hts[br*2 + 0], tt = hts[br*2 + 1];
    const unsigned short* pa = amean_bf + (size_t)(b*E_ + hh)*A_*L_;
    const unsigned short* pb = amean_bf + (size_t)(b*E_ + tt)*A_*L_;

    int l0 = threadIdx.x * 4;
    float v[4] = {0.f, 0.f, 0.f, 0.f};
    for (int a = 0; a < A_; ++a) {
        ushort4 ua = *(const ushort4*)(pa + (size_t)a*L_ + l0);
        ushort4 ub = *(const ushort4*)(pb + (size_t)a*L_ + l0);
        v[0] += bff(ua.x)*bff(ub.x); v[1] += bff(ua.y)*bff(ub.y);
        v[2] += bff(ua.z)*bff(ub.z); v[3] += bff(ua.w)*bff(ub.w);
    }
    float part = (v[0]+v[1]+v[2]+v[3]) * 0.0625f;
    __shared__ float red[256];
    red[threadIdx.x] = part;
    __syncthreads();
    for (int st = 128; st > 0; st >>= 1) {
        if (threadIdx.x < st) red[threadIdx.x] += red[threadIdx.x + st];
        __syncthreads();
    }
    float norm = 0.0625f / (red[0] + 1e-5f);
    unsigned short* po = htw_bf + (size_t)br*L_ + l0;
    po[0] = f2bf(v[0]*norm); po[1] = f2bf(v[1]*norm);
    po[2] = f2bf(v[2]*norm); po[3] = f2bf(v[3]*norm);
}

// ---------------- generic transpose+cvt: in f32 [z][K][O] -> out bf16 [z][O][K] ----------------
__global__ void k_transcvt(const float* __restrict__ W, unsigned short* __restrict__ Wt,
                           int K, int O)
{
    const float* src = W + (size_t)blockIdx.z*K*O;
    unsigned short* dst = Wt + (size_t)blockIdx.z*K*O;
    __shared__ unsigned short t[64][72];
    int k0 = blockIdx.x * 64, o0 = blockIdx.y * 64;
    #pragma unroll
    for (int p = 0; p < 16; ++p) {
        int idx = p*256 + threadIdx.x;
        int r = idx >> 6, c = idx & 63;
        t[c][r] = f2bf(src[(size_t)(k0 + r)*O + o0 + c]);
    }
    __syncthreads();
    #pragma unroll
    for (int p = 0; p < 16; ++p) {
        int idx = p*256 + threadIdx.x;
        int r = idx >> 6, c = idx & 63;
        dst[(size_t)(o0 + r)*K + k0 + c] = t[r][c];
    }
}

// ---------------- W_bil f32 [49152][768] -> W2 bf16 fragment layout ----------------
// W2[s=kb*6+ob][i][wc][f=jh*4+of][lane][e], slice = 1 MB
// elem (lane,e) of frag f = W[(kb*64+i)*64 + j][ob*128 + wc*64 + of*16 + (lane&15)]
// with j = (jh*4 + (lane>>4))*8 + e
__global__ void k_cvtW2(const float* __restrict__ W, unsigned short* __restrict__ W2)
{
    __shared__ unsigned short t[64][72];
    int k0 = blockIdx.x * 64, o0 = blockIdx.y * 64;
    #pragma unroll
    for (int p = 0; p < 16; ++p) {
        int idx = p*256 + threadIdx.x;
        int r = idx >> 6, c = idx & 63;          // r: k-local (j), c: o-local
        t[c][r] = f2bf(W[(size_t)(k0 + r)*OUT_ + o0 + c]);
    }
    __syncthreads();
    int kb = k0 >> 12;
    int i  = (k0 >> 6) & 63;
    int ob = o0 >> 7;
    int wc = (o0 >> 6) & 1;
    unsigned short* base = W2 + (size_t)(kb*6 + ob)*SLICE2_ + i*8192 + wc*4096;
    #pragma unroll
    for (int p = 0; p < 16; ++p) {
        int lin = p*256 + threadIdx.x;           // 0..4095
        int e = lin & 7;
        int lane = (lin >> 3) & 63;
        int f = lin >> 9;                        // 0..7 = jh*4 + ofl
        int jh = f >> 2, ofl = f & 3;
        int j = (jh*4 + (lane >> 4))*8 + e;
        int o_local = ofl*16 + (lane & 15);
        base[f*512 + lane*8 + e] = t[o_local][j];
    }
}

// ---------------- merged init: pacc biases + embeds bias + WcatT ----------------
__global__ void k_init(const float* __restrict__ b_head, const float* __restrict__ b_tail,
                       const float* __restrict__ b_bil,
                       const float* __restrict__ Wc, const float* __restrict__ Wbn,
                       float* __restrict__ pacc, float* __restrict__ embeds,
                       unsigned short* __restrict__ WcatT)
{
    int idx = blockIdx.x * 256 + threadIdx.x;
    if (idx < 2*NPAD_*OUT_) {
        const float* bb = (idx < NPAD_*OUT_) ? b_head : b_tail;
        pacc[idx] = bb[idx % OUT_];
    } else if (idx < 2*NPAD_*OUT_ + N_*OUT_) {
        int j = idx - 2*NPAD_*OUT_;
        embeds[j] = b_bil[j % OUT_];
    } else {
        int j = idx - 2*NPAD_*OUT_ - N_*OUT_;
        if (j < 256*768) {
            int o = j / 768, k = j % 768;
            float v = 0.f;
            if (o < NC_) v = Wc[(size_t)k*NC_ + o];
            else if (o == NC_) v = Wbn[k];
            WcatT[j] = f2bf(v);
        }
    }
}

// ---------------- rel = ht_attn @ seq : MFMA, BN=128, reg-prefetch ----------------
__global__ __launch_bounds__(256, 2)
void k_rel_mfma(const unsigned short* __restrict__ htw,   // B,R,L
                const unsigned short* __restrict__ seqT,  // B,H,L
                unsigned short* __restrict__ rel_bf)      // N,H
{
    int bid = blockIdx.x;
    int ot = bid & 7;
    int rest = bid >> 3;
    int mt = rest % 5;
    int b  = rest / 5;
    int m0 = mt*128, o0 = ot*128;
    int tid = threadIdx.x, lane = tid & 63, wid = tid >> 6;
    int wr = wid >> 1, wc = wid & 1;
    __shared__ __align__(16) unsigned short a_s[128*64];
    __shared__ __align__(16) unsigned short b_s[128*64];
    const unsigned short* Ab = htw + (size_t)b*R_*L_;
    const unsigned short* Bb = seqT + (size_t)b*H_*L_;

    u32x4 aR[4], bR[4];
    auto loadA = [&](int st) {
        #pragma unroll
        for (int q = 0; q < 4; ++q) {
            int slot = q*256 + tid;
            int r = slot >> 3, s = slot & 7;
            int ar = m0 + r; if (ar > R_-1) ar = R_-1;
            aR[q] = *(const u32x4*)(Ab + (size_t)ar*L_ + st*64 + s*8);
        }
    };
    auto loadB = [&](int st) {
        #pragma unroll
        for (int q = 0; q < 4; ++q) {
            int slot = q*256 + tid;
            int o = slot >> 3, s = slot & 7;
            bR[q] = *(const u32x4*)(Bb + (size_t)(o0+o)*L_ + st*64 + s*8);
        }
    };

    f32x4 acc[4][4];
    const f32x4 zz = {0.f,0.f,0.f,0.f};
    #pragma unroll
    for (int mf = 0; mf < 4; ++mf)
        #pragma unroll
        for (int of = 0; of < 4; ++of) acc[mf][of] = zz;

    loadA(0); loadB(0);
    for (int st = 0; st < 16; ++st) {
        __syncthreads();
        #pragma unroll
        for (int q = 0; q < 4; ++q) {
            int slot = q*256 + tid; int r = slot >> 3, s = slot & 7;
            *(u32x4*)((char*)a_s + r*128 + ((s ^ (r & 7)) << 4)) = aR[q];
        }
        #pragma unroll
        for (int q = 0; q < 4; ++q) {
            int slot = q*256 + tid; int o = slot >> 3, s = slot & 7;
            *(u32x4*)((char*)b_s + o*128 + ((s ^ (o & 7)) << 4)) = bR[q];
        }
        __syncthreads();
        if (st < 15) { loadA(st+1); loadB(st+1); }
        #pragma unroll
        for (int kh = 0; kh < 2; ++kh) {
            s16x8 af[4];
            #pragma unroll
            for (int mf = 0; mf < 4; ++mf) {
                int r = wr*64 + mf*16 + (lane & 15);
                int s = kh*4 + (lane >> 4);
                af[mf] = *(const s16x8*)((const char*)a_s + r*128 + ((s ^ (r & 7)) << 4));
            }
            #pragma unroll
            for (int of = 0; of < 4; ++of) {
                int ol = wc*64 + of*16 + (lane & 15);
                int s = kh*4 + (lane >> 4);
                s16x8 bfr = *(const s16x8*)((const char*)b_s + ol*128 + ((s ^ (ol & 7)) << 4));
                #pragma unroll
                for (int mf = 0; mf < 4; ++mf)
                    acc[mf][of] = __builtin_amdgcn_mfma_f32_16x16x32_bf16(
                        af[mf], bfr, acc[mf][of], 0, 0, 0);
            }
        }
    }
    #pragma unroll
    for (int mf = 0; mf < 4; ++mf)
        #pragma unroll
        for (int of = 0; of < 4; ++of) {
            int col = o0 + wc*64 + of*16 + (lane & 15);
            #pragma unroll
            for (int rr = 0; rr < 4; ++rr) {
                int row = m0 + wr*64 + mf*16 + (lane >> 4)*4 + rr;
                if (row < R_)
                    rel_bf[((size_t)b*R_ + row)*H_ + col] = f2bf(acc[mf][of][rr]);
            }
        }
}

// ---------------- head/tail projection MFMA, reg-prefetch ----------------
__global__ __launch_bounds__(256, 2)
void k_proj_mfma(const unsigned short* __restrict__ ent_bf,
                 const unsigned short* __restrict__ rel_bf,
                 const int* __restrict__ hts,
                 const unsigned short* __restrict__ Wph,   // 768 x 2048
                 const unsigned short* __restrict__ Wpt,
                 float* __restrict__ pacc)
{
    int bid = blockIdx.x;
    int kq = bid & 3;
    int rest = bid >> 2;
    int ob = rest % 3;  rest /= 3;
    int mb = rest % 18;
    int which = rest / 18;
    int m0 = mb * 128, o0 = ob * 256;
    const unsigned short* Wp = which ? Wpt : Wph;
    float* out = pacc + (size_t)which*NPAD_*OUT_;
    int tid = threadIdx.x, lane = tid & 63, wid = tid >> 6;
    int wr = wid >> 1, wc = wid & 1;
    __shared__ __align__(16) unsigned short a_s[128*64];
    __shared__ __align__(16) unsigned short b_s[256*64];

    bool enthalf = (kq < 2);
    const unsigned short* abase[4];
    #pragma unroll
    for (int q = 0; q < 4; ++q) {
        int slot = q*256 + tid;
        int r = slot >> 3;
        int n = m0 + r;
        int nn = (n < N_) ? n : (N_ - 1);
        if (enthalf) {
            int bb = nn / R_;
            abase[q] = ent_bf + (size_t)(bb*E_ + hts[nn*2 + which])*H_ + kq*512;
        } else {
            abase[q] = rel_bf + (size_t)nn*H_ + (kq - 2)*512;
        }
    }
    u32x4 aR[4], bR[8];
    auto loadA = [&](int st) {
        #pragma unroll
        for (int q = 0; q < 4; ++q) {
            int s = (q*256 + tid) & 7;
            aR[q] = *(const u32x4*)(abase[q] + st*64 + s*8);
        }
    };
    auto loadB = [&](int st) {
        #pragma unroll
        for (int q = 0; q < 8; ++q) {
            int slot = q*256 + tid;
            int o = slot >> 3, s = slot & 7;
            bR[q] = *(const u32x4*)(Wp + (size_t)(o0+o)*K2H_ + kq*512 + st*64 + s*8);
        }
    };

    f32x4 acc[4][8];
    const f32x4 zz = {0.f,0.f,0.f,0.f};
    #pragma unroll
    for (int mf = 0; mf < 4; ++mf)
        #pragma unroll
        for (int of = 0; of < 8; ++of) acc[mf][of] = zz;

    loadA(0); loadB(0);
    for (int st = 0; st < 8; ++st) {
        __syncthreads();
        #pragma unroll
        for (int q = 0; q < 4; ++q) {
            int slot = q*256 + tid; int r = slot >> 3, s = slot & 7;
            *(u32x4*)((char*)a_s + r*128 + ((s ^ (r & 7)) << 4)) = aR[q];
        }
        #pragma unroll
        for (int q = 0; q < 8; ++q) {
            int slot = q*256 + tid; int o = slot >> 3, s = slot & 7;
            *(u32x4*)((char*)b_s + o*128 + ((s ^ (o & 7)) << 4)) = bR[q];
        }
        __syncthreads();
        if (st < 7) { loadA(st+1); loadB(st+1); }
        #pragma unroll
        for (int kh = 0; kh < 2; ++kh) {
            s16x8 af[4];
            #pragma unroll
            for (int mf = 0; mf < 4; ++mf) {
                int r = wr*64 + mf*16 + (lane & 15);
                int s = kh*4 + (lane >> 4);
                af[mf] = *(const s16x8*)((const char*)a_s + r*128 + ((s ^ (r & 7)) << 4));
            }
            #pragma unroll
            for (int of = 0; of < 8; ++of) {
                int ol = wc*128 + of*16 + (lane & 15);
                int s = kh*4 + (lane >> 4);
                s16x8 bfr = *(const s16x8*)((const char*)b_s + ol*128 + ((s ^ (ol & 7)) << 4));
                #pragma unroll
                for (int mf = 0; mf < 4; ++mf)
                    acc[mf][of] = __builtin_amdgcn_mfma_f32_16x16x32_bf16(
                        af[mf], bfr, acc[mf][of], 0, 0, 0);
            }
        }
    }
    #pragma unroll
    for (int mf = 0; mf < 4; ++mf)
        #pragma unroll
        for (int of = 0; of < 8; ++of) {
            int col = o0 + wc*128 + of*16 + (lane & 15);
            #pragma unroll
            for (int rr = 0; rr < 4; ++rr) {
                int row = m0 + wr*64 + mf*16 + (lane >> 4)*4 + rr;
                atomicAdd(&out[(size_t)row*OUT_ + col], acc[mf][of][rr]);
            }
        }
}

// ---------------- tanh + cvt ----------------
__global__ void k_tanhcvt(const float* __restrict__ pacc,
                          unsigned short* __restrict__ hsp,
                          unsigned short* __restrict__ tsp)
{
    int idx = blockIdx.x * 256 + threadIdx.x;
    if (idx < NPAD_*OUT_) {
        hsp[idx] = f2bf(tanhf(pacc[idx]));
        tsp[idx] = f2bf(tanhf(pacc[NPAD_*OUT_ + idx]));
    }
}

// ---------------- bilinear MFMA GEMM (round-12 structure; best measured 206 us) ----------------
// grid 1296 = 8 XCD x 9 g x 18 mb; slice s = g*8+x in [0,72): kb = s/6, ob = s%6.
// Block 128M x 128o, 4 waves (2wr x 2wc), wave 64x64 (Fm=4, Fo=4).
// W2 frags loaded straight to registers (L2-resident), 2-deep named dbuf, no K-loop barriers.
// bounds MUST stay (256,2): this kernel needs ~112 VGPR; bounds-3 (r10, cap 84) and
// bounds-4 (r16, cap 64) both spilled bA/bB to scratch (4.6-4.8 GB/dispatch, 6-8x slower).
__global__ __launch_bounds__(256, 2)
void k_bilinear_mfma(const unsigned short* __restrict__ hsp,
                     const unsigned short* __restrict__ tsp,
                     const unsigned short* __restrict__ W2,
                     float* __restrict__ embeds)
{
    int bid = blockIdx.x;
    int x = bid & 7, rest = bid >> 3;     // rest 0..161
    int g = rest / 18, mb = rest % 18;    // g 0..8
    int s = g*8 + x;                      // 0..71
    int kb = s / 6, ob = s % 6;
    int m0 = mb * 128;
    int tid = threadIdx.x, lane = tid & 63, wid = tid >> 6;
    int wr = wid >> 1, wc = wid & 1;

    __shared__ __align__(16) unsigned short hs_s[128*64];  // 16 KB
    __shared__ __align__(16) unsigned short ts_s[128*64];  // 16 KB

    // ---- prologue: stage hs/ts tiles (XOR-swizzled src, linear dst) ----
    #pragma unroll
    for (int q = 0; q < 4; ++q) {
        int slot = q*256 + tid;
        int r = slot >> 3, s7 = slot & 7;
        int gg = s7 ^ (r & 7);
        size_t srcoff = (size_t)(m0 + r)*EMB_ + kb*64 + (gg << 3);
        gload_lds16(hsp + srcoff, (char*)hs_s + (q*4096 + wid*1024));
        gload_lds16(tsp + srcoff, (char*)ts_s + (q*4096 + wid*1024));
    }
    __syncthreads();

    // ---- ts fragments -> unpacked f32 regs (Fm=4) ----
    float tsf[4][2][8];
    #pragma unroll
    for (int mf = 0; mf < 4; ++mf) {
        int r = wr*64 + mf*16 + (lane & 15);
        #pragma unroll
        for (int jh = 0; jh < 2; ++jh) {
            int s8 = jh*4 + (lane >> 4);
            u32x4 tv = *(const u32x4*)((const char*)ts_s + r*128 + ((s8 ^ (r & 7)) << 4));
            #pragma unroll
            for (int p = 0; p < 4; ++p) {
                tsf[mf][jh][2*p]   = __builtin_bit_cast(float, tv[p] << 16);
                tsf[mf][jh][2*p+1] = __builtin_bit_cast(float, tv[p] & 0xffff0000u);
            }
        }
    }

    const unsigned short* Wsl = W2 + (size_t)s * SLICE2_ + wc*4096 + lane*8;

    f32x4 acc[4][4];
    const f32x4 zz = {0.f, 0.f, 0.f, 0.f};
    #pragma unroll
    for (int mf = 0; mf < 4; ++mf)
        #pragma unroll
        for (int of = 0; of < 4; ++of) acc[mf][of] = zz;

    u32x4 bA[8], bB[8];
    auto loadB = [&](int i, u32x4 (&buf)[8]) {
        const unsigned short* src = Wsl + (size_t)i*8192;
        #pragma unroll
        for (int f = 0; f < 8; ++f)
            buf[f] = *(const u32x4*)(src + f*512);
    };
    auto compute = [&](int i, u32x4 (&buf)[8]) {
        float hsf[4];
        #pragma unroll
        for (int mf = 0; mf < 4; ++mf) {
            int r = wr*64 + mf*16 + (lane & 15);
            int hb = r*128 + ((((i >> 3)) ^ (r & 7)) << 4) + (i & 7)*2;
            hsf[mf] = bff(*(const unsigned short*)((const char*)hs_s + hb));
        }
        #pragma unroll
        for (int jh = 0; jh < 2; ++jh) {
            s16x8 afr[4];
            #pragma unroll
            for (int mf = 0; mf < 4; ++mf) {
                u32x4 a;
                #pragma unroll
                for (int p = 0; p < 4; ++p)
                    a[p] = pkbf16(hsf[mf]*tsf[mf][jh][2*p], hsf[mf]*tsf[mf][jh][2*p+1]);
                afr[mf] = __builtin_bit_cast(s16x8, a);
            }
            __builtin_amdgcn_s_setprio(1);
            #pragma unroll
            for (int of = 0; of < 4; ++of) {
                s16x8 bfr = __builtin_bit_cast(s16x8, buf[jh*4 + of]);
                #pragma unroll
                for (int mf = 0; mf < 4; ++mf)
                    acc[mf][of] = __builtin_amdgcn_mfma_f32_16x16x32_bf16(
                        afr[mf], bfr, acc[mf][of], 0, 0, 0);
            }
            __builtin_amdgcn_s_setprio(0);
        }
    };

    loadB(0, bA);
    for (int i2 = 0; i2 < 32; ++i2) {
        loadB(2*i2 + 1, bB);               // prefetch odd
        compute(2*i2, bA);
        if (i2 < 31) loadB(2*i2 + 2, bA);  // prefetch next even
        compute(2*i2 + 1, bB);
    }

    // ---- atomic accumulate ----
    #pragma unroll
    for (int mf = 0; mf < 4; ++mf) {
        #pragma unroll
        for (int of = 0; of < 4; ++of) {
            int col = ob*128 + wc*64 + of*16 + (lane & 15);
            #pragma unroll
            for (int rr = 0; rr < 4; ++rr) {
                int row = wr*64 + mf*16 + (lane >> 4)*4 + rr;
                int n = m0 + row;
                if (n < N_)
                    atomicAdd(&embeds[(size_t)n*OUT_ + col], acc[mf][of][rr]);
            }
        }
    }
}

// ---------------- logits MFMA: reads f32 embeds directly (cvt in reg-staging) ----------------
__global__ __launch_bounds__(256, 2)
void k_logits_mfma(const float* __restrict__ embeds,        // N x 768 f32
                   const unsigned short* __restrict__ WcatT,// 256 x 768 bf16
                   const float* __restrict__ bc, const float* __restrict__ bbn,
                   float* __restrict__ cls, float* __restrict__ bin)
{
    int m0 = blockIdx.x * 128;
    int tid = threadIdx.x, lane = tid & 63, wid = tid >> 6;
    int wr = wid >> 1, wc = wid & 1;
    __shared__ __align__(16) unsigned short a_s[128*64];
    __shared__ __align__(16) unsigned short b_s[256*64];

    u32x4 aR[4], bR[8];
    auto loadA = [&](int st) {
        #pragma unroll
        for (int q = 0; q < 4; ++q) {
            int slot = q*256 + tid;
            int r = slot >> 3, s = slot & 7;
            int ar = m0 + r; if (ar > N_-1) ar = N_-1;
            const float* src = embeds + (size_t)ar*OUT_ + st*64 + s*8;
            float4 v0 = *(const float4*)(src);
            float4 v1 = *(const float4*)(src + 4);
            u32x4 a;
            a[0] = pkbf16(v0.x, v0.y); a[1] = pkbf16(v0.z, v0.w);
            a[2] = pkbf16(v1.x, v1.y); a[3] = pkbf16(v1.z, v1.w);
            aR[q] = a;
        }
    };
    auto loadB = [&](int st) {
        #pragma unroll
        for (int q = 0; q < 8; ++q) {
            int slot = q*256 + tid;
            int o = slot >> 3, s = slot & 7;
            bR[q] = *(const u32x4*)(WcatT + (size_t)o*OUT_ + st*64 + s*8);
        }
    };

    f32x4 acc[4][8];
    const f32x4 zz = {0.f,0.f,0.f,0.f};
    #pragma unroll
    for (int mf = 0; mf < 4; ++mf)
        #pragma unroll
        for (int of = 0; of < 8; ++of) acc[mf][of] = zz;

    loadA(0); loadB(0);
    for (int st = 0; st < 12; ++st) {
        __syncthreads();
        #pragma unroll
        for (int q = 0; q < 4; ++q) {
            int slot = q*256 + tid; int r = slot >> 3, s = slot & 7;
            *(u32x4*)((char*)a_s + r*128 + ((s ^ (r & 7)) << 4)) = aR[q];
        }
        #pragma unroll
        for (int q = 0; q < 8; ++q) {
            int slot = q*256 + tid; int o = slot >> 3, s = slot & 7;
            *(u32x4*)((char*)b_s + o*128 + ((s ^ (o & 7)) << 4)) = bR[q];
        }
        __syncthreads();
        if (st < 11) { loadA(st+1); loadB(st+1); }
        #pragma unroll
        for (int kh = 0; kh < 2; ++kh) {
            s16x8 af[4];
            #pragma unroll
            for (int mf = 0; mf < 4; ++mf) {
                int r = wr*64 + mf*16 + (lane & 15);
                int s = kh*4 + (lane >> 4);
                af[mf] = *(const s16x8*)((const char*)a_s + r*128 + ((s ^ (r & 7)) << 4));
            }
            #pragma unroll
            for (int of = 0; of < 8; ++of) {
                int ol = wc*128 + of*16 + (lane & 15);
                int s = kh*4 + (lane >> 4);
                s16x8 bfr = *(const s16x8*)((const char*)b_s + ol*128 + ((s ^ (ol & 7)) << 4));
                #pragma unroll
                for (int mf = 0; mf < 4; ++mf)
                    acc[mf][of] = __builtin_amdgcn_mfma_f32_16x16x32_bf16(
                        af[mf], bfr, acc[mf][of], 0, 0, 0);
            }
        }
    }
    #pragma unroll
    for (int mf = 0; mf < 4; ++mf)
        #pragma unroll
        for (int of = 0; of < 8; ++of) {
            int col = wc*128 + of*16 + (lane & 15);
            if (col <= NC_) {
                #pragma unroll
                for (int rr = 0; rr < 4; ++rr) {
                    int row = m0 + wr*64 + mf*16 + (lane >> 4)*4 + rr;
                    if (row < N_) {
                        float v = acc[mf][of][rr];
                        if (col < NC_) cls[(size_t)row*NC_ + col] = v + bc[col];
                        else           bin[row] = v + bbn[0];
                    }
                }
            }
        }
}

extern "C" void kernel_launch(void* const* d_in, const int* in_sizes, int n_in,
                              void* d_out, int out_size, void* d_ws, size_t ws_size,
                              hipStream_t stream) {
    const float* seq_lhs = (const float*)d_in[0];
    const float* ent_lhs = (const float*)d_in[1];
    const float* attn    = (const float*)d_in[2];
    const int*   labels  = (const int*)d_in[3];
    const int*   hts     = (const int*)d_in[4];
    const float* W_head  = (const float*)d_in[5];
    const float* b_head  = (const float*)d_in[6];
    const float* W_tail  = (const float*)d_in[7];
    const float* b_tail  = (const float*)d_in[8];
    const float* W_bil   = (const float*)d_in[9];
    const float* b_bil   = (const float*)d_in[10];
    const float* W_cls   = (const float*)d_in[11];
    const float* b_cls   = (const float*)d_in[12];
    const float* W_bin   = (const float*)d_in[13];
    const float* b_bin   = (const float*)d_in[14];

    float* out_embeds = (float*)d_out;
    float* out_cls    = out_embeds + (size_t)N_*OUT_;
    float* out_bin    = out_cls + (size_t)N_*NC_;

    float* ws = (float*)d_ws;
    size_t off = 0;
    unsigned short* ent_bf   = (unsigned short*)(ws + off); off += (size_t)B_*E_*H_/2;
    float* pacc = ws + off;   // overlays amean_bf + htw_bf + seqT (dead by then)
    unsigned short* amean_bf = (unsigned short*)(ws + off); off += (size_t)B_*E_*A_*L_/2;
    unsigned short* htw_bf   = (unsigned short*)(ws + off); off += (size_t)B_*R_*L_/2;
    unsigned short* seqT     = (unsigned short*)(ws + off); off += (size_t)B_*H_*L_/2;
    unsigned short* rel_bf   = (unsigned short*)(ws + off); off += (size_t)N_*H_/2;
    unsigned short* hsp      = (unsigned short*)(ws + off); off += (size_t)NPAD_*EMB_/2;
    unsigned short* tsp      = (unsigned short*)(ws + off); off += (size_t)NPAD_*EMB_/2;
    unsigned short* W2       = (unsigned short*)(ws + off); off += (size_t)OUT_*KTOT_/2;
    unsigned short* Wph      = (unsigned short*)(ws + off); off += (size_t)OUT_*K2H_/2;
    unsigned short* Wpt      = (unsigned short*)(ws + off); off += (size_t)OUT_*K2H_/2;
    unsigned short* WcatT    = (unsigned short*)(ws + off); off += (size_t)256*768/2;

    // weight / input conversions
    k_cvtW2<<<dim3(KTOT_/64, OUT_/64), 256, 0, stream>>>(W_bil, W2);
    k_transcvt<<<dim3(K2H_/64, OUT_/64, 1), 256, 0, stream>>>(W_head, Wph, K2H_, OUT_);
    k_transcvt<<<dim3(K2H_/64, OUT_/64, 1), 256, 0, stream>>>(W_tail, Wpt, K2H_, OUT_);
    k_transcvt<<<dim3(L_/64, H_/64, B_), 256, 0, stream>>>(seq_lhs, seqT, L_, H_);

    k_pool<<<B_*E_, 256, 0, stream>>>(ent_lhs, attn, labels, ent_bf, amean_bf);
    k_htattn<<<B_*R_, 256, 0, stream>>>(amean_bf, hts, htw_bf);
    k_rel_mfma<<<160, 256, 0, stream>>>(htw_bf, seqT, rel_bf);

    // pacc overlays amean/htw/seqT -- init only after k_rel consumed them
    int init_elems = 2*NPAD_*OUT_ + N_*OUT_ + 256*768;
    k_init<<<(init_elems + 255)/256, 256, 0, stream>>>(b_head, b_tail, b_bil,
                                                       W_cls, W_bin,
                                                       pacc, out_embeds, WcatT);
    k_proj_mfma<<<2*18*3*4, 256, 0, stream>>>(ent_bf, rel_bf, hts, Wph, Wpt, pacc);
    k_tanhcvt<<<(NPAD_*OUT_ + 255)/256, 256, 0, stream>>>(pacc, hsp, tsp);

    k_bilinear_mfma<<<1296, 256, 0, stream>>>(hsp, tsp, W2, out_embeds);

    k_logits_mfma<<<18, 256, 0, stream>>>(out_embeds, WcatT, b_cls, b_bin,
                                          out_cls, out_bin);
}